// Round 1
// baseline (1583.119 us; speedup 1.0000x reference)
//
#include <hip/hip_runtime.h>
#include <hip/hip_bf16.h>
#include <hip/hip_fp16.h>
#include <cstdint>

#define DI 1024
#define SL 2048
#define HD 64
#define BA 16
#define KAUG 1088   // 1024 + 64 augmented K for fused scores GEMM

typedef _Float16 f16;
typedef _Float16 f16x8 __attribute__((ext_vector_type(8)));
typedef _Float16 f16x4 __attribute__((ext_vector_type(4)));
typedef float    f32x4 __attribute__((ext_vector_type(4)));

// ---------------------------------------------------------------------------
// async global->LDS 16B copy. LDS dest is wave-uniform base + lane*16 (HW rule).
// Generic->AS3 via uintptr truncation (low 32 bits of generic LDS addr = LDS offset).
// ---------------------------------------------------------------------------
typedef __attribute__((address_space(1))) void gvoid_t;
typedef __attribute__((address_space(3))) void lvoid_t;

__device__ __forceinline__ void async16(const void* g, void* l) {
    __builtin_amdgcn_global_load_lds((gvoid_t*)(uintptr_t)g,
                                     (lvoid_t*)(unsigned int)(uintptr_t)l,
                                     16, 0, 0);
}

// ---------------------------------------------------------------------------
// fp32 -> fp16 elementwise convert (vectorized)
// ---------------------------------------------------------------------------
__global__ __launch_bounds__(256) void cvt_f16v(const float* __restrict__ in,
                                                f16* __restrict__ out, int n4) {
    int i = blockIdx.x * 256 + threadIdx.x;
    if (i < n4) {
        float4 v = ((const float4*)in)[i];
        f16x4 h;
        h[0] = (f16)v.x; h[1] = (f16)v.y; h[2] = (f16)v.z; h[3] = (f16)v.w;
        *(f16x4*)(out + (long)i * 4) = h;
    }
}

// ---------------------------------------------------------------------------
// transpose + convert: in fp32 [R][C] -> out fp16 [C][R]  (batched via z)
// ---------------------------------------------------------------------------
__global__ __launch_bounds__(256) void transpose_cvt(const float* __restrict__ in,
                                                     f16* __restrict__ out,
                                                     int R, int C, long sIn, long sOut) {
    __shared__ float tile[32][33];
    const int b = blockIdx.z;
    in  += (long)b * sIn;
    out += (long)b * sOut;
    int c0 = blockIdx.x * 32, r0 = blockIdx.y * 32;
    int tx = threadIdx.x & 31, ty = threadIdx.x >> 5;   // 32 x 8
#pragma unroll
    for (int i = 0; i < 32; i += 8) {
        int r = r0 + ty + i;
        if (r < R && c0 + tx < C) tile[ty + i][tx] = in[(long)r * C + c0 + tx];
    }
    __syncthreads();
#pragma unroll
    for (int i = 0; i < 32; i += 8) {
        int c = c0 + ty + i;
        if (c < C && r0 + tx < R) out[(long)c * R + r0 + tx] = (f16)tile[tx][ty + i];
    }
}

// ---------------------------------------------------------------------------
// fill ka[b][t][1024+j] = w2[j][t]  (w2 is [64][2048])
// ---------------------------------------------------------------------------
__global__ __launch_bounds__(256) void fill_ka(const float* __restrict__ w2,
                                               f16* __restrict__ ka) {
    long idx = (long)blockIdx.x * 256 + threadIdx.x;   // BA*SL*HD total
    int  j   = (int)(idx & 63);
    long bt  = idx >> 6;                                // 0..BA*SL-1
    int  t   = (int)(bt & (SL - 1));
    ka[bt * KAUG + DI + j] = (f16)w2[(long)j * SL + t];
}

// ---------------------------------------------------------------------------
// Tiled MFMA GEMM:  C[M][N] = A[M][K] * Bt[N][K]^T  (+bias / relu / exp epilogue)
// BM=BN=128, BK=64, 256 threads (4 waves as 2x2 of 64x64), fp16 MFMA 16x16x32.
// EPI: 0 = store f32 (no bias)     (attn @ V)
//      1 = +bias, store f16        (q/k projections)
//      2 = +bias, relu, store f16  (synthesizer hidden h)
//      3 = +bias, exp, store f32   (scores -> unnormalized softmax numerator)
// ---------------------------------------------------------------------------
template <int EPI>
__global__ __launch_bounds__(256) void gemm_bt(const f16* __restrict__ A,
                                               const f16* __restrict__ Bt,
                                               const float* __restrict__ bias,
                                               void* __restrict__ Cout,
                                               int Nact, int K, int lda, int ldb, int ldc,
                                               long sA, long sB, long sC) {
    __shared__ alignas(16) f16 As[128][64];
    __shared__ alignas(16) f16 Bs[128][64];

    const int b = blockIdx.z;
    A  += (long)b * sA;
    Bt += (long)b * sB;

    const int tid  = threadIdx.x;
    const int w    = tid >> 6;        // wave 0..3
    const int l    = tid & 63;        // lane
    const int wm   = w >> 1;          // wave row (0..1)
    const int wn   = w & 1;           // wave col (0..1)
    const int quad = l >> 4;
    const int lm   = l & 15;
    const int tm   = blockIdx.x * 128;
    const int tn   = blockIdx.y * 128;
    const int rl   = l >> 3;          // staging row within 8-row group
    const int cl   = l & 7;           // staging 16B chunk

    f32x4 acc[4][4];
#pragma unroll
    for (int i = 0; i < 4; i++)
#pragma unroll
        for (int j = 0; j < 4; j++)
#pragma unroll
            for (int r = 0; r < 4; r++) acc[i][j][r] = 0.f;

    for (int k0 = 0; k0 < K; k0 += 64) {
#pragma unroll
        for (int i = 0; i < 4; i++) {
            int ra = tm + w * 32 + i * 8 + rl;                 // M always multiple of 128
            async16(A + (long)ra * lda + k0 + cl * 8, &As[w * 32 + i * 8][0]);
            int rb = tn + w * 32 + i * 8 + rl;
            if (rb > Nact - 1) rb = Nact - 1;                  // N edge clamp (h GEMM)
            async16(Bt + (long)rb * ldb + k0 + cl * 8, &Bs[w * 32 + i * 8][0]);
        }
        __syncthreads();
#pragma unroll
        for (int kk = 0; kk < 2; kk++) {
            f16x8 av[4], bv[4];
#pragma unroll
            for (int mi = 0; mi < 4; mi++)
                av[mi] = *(const f16x8*)&As[wm * 64 + mi * 16 + lm][kk * 32 + quad * 8];
#pragma unroll
            for (int ni = 0; ni < 4; ni++)
                bv[ni] = *(const f16x8*)&Bs[wn * 64 + ni * 16 + lm][kk * 32 + quad * 8];
#pragma unroll
            for (int mi = 0; mi < 4; mi++)
#pragma unroll
                for (int ni = 0; ni < 4; ni++)
                    acc[mi][ni] = __builtin_amdgcn_mfma_f32_16x16x32_f16(
                        av[mi], bv[ni], acc[mi][ni], 0, 0, 0);
        }
        __syncthreads();
    }

    // epilogue: D row = quad*4 + reg, col = lane&15 (verified layout, m89/m91)
#pragma unroll
    for (int ni = 0; ni < 4; ni++) {
        int col = tn + wn * 64 + ni * 16 + lm;
        if (col >= Nact) continue;
        float bvv = (EPI == 0) ? 0.f : bias[col];
#pragma unroll
        for (int mi = 0; mi < 4; mi++) {
            int row = tm + wm * 64 + mi * 16 + quad * 4;
#pragma unroll
            for (int r = 0; r < 4; r++) {
                float v = acc[mi][ni][r] + bvv;
                if (EPI == 2) v = fmaxf(v, 0.f);
                if (EPI == 3) v = __expf(v);   // logits bounded ~|60| -> no overflow
                long idx = (long)b * sC + (long)(row + r) * ldc + col;
                if (EPI == 1 || EPI == 2) ((f16*)Cout)[idx] = (f16)v;
                else                      ((float*)Cout)[idx] = v;
            }
        }
    }
}

// ---------------------------------------------------------------------------
// row normalize: e (fp32, len 2048 rows) -> e/sum in place + fp16 copy
// ---------------------------------------------------------------------------
__global__ __launch_bounds__(256) void rownorm(float* __restrict__ e,
                                               f16* __restrict__ a16) {
    __shared__ float red[4];
    const long row = blockIdx.x;
    float* p = e + row * (long)SL;
    const float4* p4 = (const float4*)p;
    const int t = threadIdx.x;

    float4 v1 = p4[t];
    float4 v2 = p4[t + 256];
    float s = v1.x + v1.y + v1.z + v1.w + v2.x + v2.y + v2.z + v2.w;
#pragma unroll
    for (int off = 1; off < 64; off <<= 1) s += __shfl_xor(s, off, 64);
    if ((t & 63) == 0) red[t >> 6] = s;
    __syncthreads();
    float inv = 1.0f / (red[0] + red[1] + red[2] + red[3]);

    float4 a1, a2;
    a1.x = v1.x * inv; a1.y = v1.y * inv; a1.z = v1.z * inv; a1.w = v1.w * inv;
    a2.x = v2.x * inv; a2.y = v2.y * inv; a2.z = v2.z * inv; a2.w = v2.w * inv;
    ((float4*)p)[t]       = a1;
    ((float4*)p)[t + 256] = a2;

    f16x4 h1, h2;
    h1[0] = (f16)a1.x; h1[1] = (f16)a1.y; h1[2] = (f16)a1.z; h1[3] = (f16)a1.w;
    h2[0] = (f16)a2.x; h2[1] = (f16)a2.y; h2[2] = (f16)a2.z; h2[3] = (f16)a2.w;
    *(f16x4*)(a16 + row * (long)SL + t * 4)        = h1;
    *(f16x4*)(a16 + row * (long)SL + 1024 + t * 4) = h2;
}

// ---------------------------------------------------------------------------
extern "C" void kernel_launch(void* const* d_in, const int* in_sizes, int n_in,
                              void* d_out, int out_size, void* d_ws, size_t ws_size,
                              hipStream_t stream) {
    const float* query = (const float*)d_in[0];
    const float* key   = (const float*)d_in[1];
    const float* value = (const float*)d_in[2];
    const float* w1    = (const float*)d_in[3];
    const float* b1    = (const float*)d_in[4];
    const float* w2    = (const float*)d_in[5];
    const float* b2    = (const float*)d_in[6];
    const float* wq    = (const float*)d_in[7];
    const float* bq    = (const float*)d_in[8];
    const float* wk    = (const float*)d_in[9];
    const float* bk    = (const float*)d_in[10];

    float* out_o = (float*)d_out;                          // [16,2048,1024]
    float* out_a = out_o + (long)BA * SL * DI;             // [16,2048,2048]

    // workspace layout (fp16 elements); total ~332 MiB
    f16* q16    = (f16*)d_ws;                              // 33.5M  (query fp16)
    f16* k16    = q16 + (long)BA * SL * DI;                // 33.5M  (key fp16)
    f16* attn16 = q16;                                     // alias: q16+k16 dead by then
    f16* qa     = k16 + (long)BA * SL * DI;                // [32768][1088]  q | h
    f16* ka     = qa + (long)BA * SL * KAUG;               // [32768][1088]  k | w2^T
    f16* vT     = ka + (long)BA * SL * KAUG;               // [16][1024][2048]
    f16* wqT    = vT + (long)BA * SL * DI;                 // [1024][1024]
    f16* wkT    = wqT + (long)DI * DI;
    f16* w1T    = wkT + (long)DI * DI;                     // [64][1024]

    const long nQK = (long)BA * SL * DI;                   // 33,554,432

    // 1. fp32 -> fp16 copies of query/key (A operands of projection GEMMs)
    cvt_f16v<<<(int)(nQK / 4 / 256), 256, 0, stream>>>(query, q16, (int)(nQK / 4));
    cvt_f16v<<<(int)(nQK / 4 / 256), 256, 0, stream>>>(key,   k16, (int)(nQK / 4));

    // 2. weight / value transposes into B^T layout (fp16)
    transpose_cvt<<<dim3(32, 32, 1), 256, 0, stream>>>(wq, wqT, DI, DI, 0, 0);
    transpose_cvt<<<dim3(32, 32, 1), 256, 0, stream>>>(wk, wkT, DI, DI, 0, 0);
    transpose_cvt<<<dim3(2, 32, 1), 256, 0, stream>>>(w1, w1T, DI, HD, 0, 0);
    transpose_cvt<<<dim3(DI / 32, SL / 32, BA), 256, 0, stream>>>(
        value, vT, SL, DI, (long)SL * DI, (long)DI * SL);
    fill_ka<<<BA * SL * HD / 256, 256, 0, stream>>>(w2, ka);

    // 3. projections into augmented buffers
    gemm_bt<1><<<dim3(BA * SL / 128, DI / 128, 1), 256, 0, stream>>>(
        q16, wqT, bq, qa, DI, DI, DI, DI, KAUG, 0, 0, 0);
    gemm_bt<1><<<dim3(BA * SL / 128, DI / 128, 1), 256, 0, stream>>>(
        k16, wkT, bk, ka, DI, DI, DI, DI, KAUG, 0, 0, 0);
    gemm_bt<2><<<dim3(BA * SL / 128, 1, 1), 256, 0, stream>>>(
        q16, w1T, b1, qa + DI, HD, DI, DI, DI, KAUG, 0, 0, 0);

    // 4. fused scores: exp(q.k^T + h.w2 + b2) -> d_out attention region (fp32)
    gemm_bt<3><<<dim3(SL / 128, SL / 128, BA), 256, 0, stream>>>(
        qa, ka, b2, out_a, SL, KAUG, KAUG, KAUG, SL,
        (long)SL * KAUG, (long)SL * KAUG, (long)SL * SL);

    // 5. softmax row-normalize (in place) + fp16 copy for final GEMM
    rownorm<<<BA * SL, 256, 0, stream>>>(out_a, attn16);

    // 6. out = attention @ value
    gemm_bt<0><<<dim3(SL / 128, DI / 128, BA), 256, 0, stream>>>(
        attn16, vT, nullptr, out_o, DI, SL, SL, SL, DI,
        (long)SL * SL, (long)DI * SL, (long)SL * DI);
}